// Round 4
// baseline (513.570 us; speedup 1.0000x reference)
//
#include <hip/hip_runtime.h>
#include <hip/hip_bf16.h>

// QuantizedLinear: y[m][n] = scale * sum_k x[m][k]*(q[n][k]-zp) + bias[n]
// M=8192, N=4096, K=4096. (q-zp) integer in [-255,255] -> exact in bf16.
// cvt passes -> 256^2 pipelined-fragment 4-phase bf16 MFMA GEMM.
// Phase p prefetches phase p+1's fragments; compiler emits counted lgkm waits.

typedef __attribute__((ext_vector_type(8))) __bf16 bf16x8;
typedef __attribute__((ext_vector_type(4))) float f32x4;
typedef __attribute__((ext_vector_type(4))) int i32x4;
typedef __attribute__((ext_vector_type(8))) unsigned short u16x8;

#define M_DIM 8192
#define N_DIM 4096
#define K_DIM 4096
#define BM 256
#define BN 256
#define BK 64
#define NT (K_DIM / BK)

#define MFMA16(A, B, C) __builtin_amdgcn_mfma_f32_16x16x32_bf16(A, B, C, 0, 0, 0)

__device__ __forceinline__ unsigned short f2bf(float f) {
  __hip_bfloat16 h = __float2bfloat16(f);
  unsigned short u;
  __builtin_memcpy(&u, &h, 2);
  return u;
}

// ---- conversion pass 1: x fp32 -> bf16 ----
__global__ __launch_bounds__(256) void cvt_x_kernel(const float* __restrict__ x,
                                                    unsigned short* __restrict__ out) {
  size_t i = (size_t)blockIdx.x * 256 + threadIdx.x;
  f32x4 a = ((const f32x4*)x)[2 * i];
  f32x4 b = ((const f32x4*)x)[2 * i + 1];
  u16x8 o;
  o[0] = f2bf(a[0]); o[1] = f2bf(a[1]); o[2] = f2bf(a[2]); o[3] = f2bf(a[3]);
  o[4] = f2bf(b[0]); o[5] = f2bf(b[1]); o[6] = f2bf(b[2]); o[7] = f2bf(b[3]);
  *(u16x8*)(out + 8 * i) = o;
}

// ---- conversion pass 2: w = (float)q - zp -> bf16 (exact) ----
__global__ __launch_bounds__(256) void cvt_w_kernel(const int* __restrict__ q,
                                                    const float* __restrict__ zp_ptr,
                                                    unsigned short* __restrict__ out) {
  const float zp = *zp_ptr;
  size_t i = (size_t)blockIdx.x * 256 + threadIdx.x;
  i32x4 a = ((const i32x4*)q)[2 * i];
  i32x4 b = ((const i32x4*)q)[2 * i + 1];
  u16x8 o;
  o[0] = f2bf((float)a[0] - zp); o[1] = f2bf((float)a[1] - zp);
  o[2] = f2bf((float)a[2] - zp); o[3] = f2bf((float)a[3] - zp);
  o[4] = f2bf((float)b[0] - zp); o[5] = f2bf((float)b[1] - zp);
  o[6] = f2bf((float)b[2] - zp); o[7] = f2bf((float)b[3] - zp);
  *(u16x8*)(out + 8 * i) = o;
}

// Swizzled LDS fragment read: tile is [256 rows][64 bf16], row stride 128B.
// XOR byte bits 4-6 with row bits 0-2 -> ds_read_b128 is bank-uniform.
__device__ __forceinline__ bf16x8 lds_frag(const char* base, int row, int ks, int lh) {
  int byte = row * 128 + ks * 64 + lh * 16;
  byte ^= ((byte >> 7) & 7) << 4;
  return *(const bf16x8*)(base + byte);
}

// Stage one half-tile (128 rows x 64 bf16 = 16KB): 8 waves x 2 chunks x 1KB.
// LDS dest linear (HW: base + lane*16); global source inverse-swizzled.
__device__ __forceinline__ void stage_half(const unsigned short* __restrict__ g,
                                           size_t grow0, int k0, char* lds,
                                           int tileOff, int h, int w, int lane) {
#pragma unroll
  for (int j = 0; j < 2; ++j) {
    const int chunk = (w * 2 + j) * 1024;
    const int d = h * 16384 + chunk + lane * 16;        // linear dest byte in tile
    const int sd = d ^ (((d >> 7) & 7) << 4);           // swizzle (involution)
    const int row = sd >> 7;
    const int colB = sd & 127;
    const char* src = (const char*)g + ((grow0 + row) * (size_t)K_DIM + k0) * 2 + colB;
    __builtin_amdgcn_global_load_lds(
        (const __attribute__((address_space(1))) void*)src,
        (__attribute__((address_space(3))) void*)(lds + tileOff + h * 16384 + chunk),
        16, 0, 0);
  }
}

// ---- 256x256 GEMM, 4 phases/K-tile, fragment reads pipelined 1 phase ahead ----
__global__ __launch_bounds__(512, 2) void gemm8_kernel(
    const unsigned short* __restrict__ A, const unsigned short* __restrict__ B,
    const float* __restrict__ scale_ptr, const float* __restrict__ bias,
    float* __restrict__ C) {
  __shared__ __align__(16) char lds[131072];  // buf c: A @ c*65536, B @ c*65536+32768

  const int t = threadIdx.x;
  const int lane = t & 63;
  const int w = t >> 6;      // 0..7
  const int wm = w >> 2;     // 0..1
  const int wn = w & 3;      // 0..3
  const int ll = lane & 15;
  const int lh = lane >> 4;

  // T1: bijective XCD swizzle (nwg = 512, 512 % 8 == 0)
  const int nwg = gridDim.x * gridDim.y;
  const int flat = blockIdx.y * gridDim.x + blockIdx.x;
  const int per = nwg >> 3;
  const int sw = (flat & 7) * per + (flat >> 3);
  const int tn = sw & (N_DIM / BN - 1);
  const int tm = sw / (N_DIM / BN);
  const size_t gm0 = (size_t)tm * BM;
  const size_t gn0 = (size_t)tn * BN;

  f32x4 acc[8][4] = {};  // [mh*4+fi][nh*2+fj]
  bf16x8 a0[4][2], a1[4][2], b0[2][2], b1[2][2];

  // ---- prologue: stage tile0 fully; pre-read a0,b0; stage tile1 (B h0,h1 + A h0) ----
  stage_half(A, gm0, 0, lds, 0, 0, w, lane);
  stage_half(A, gm0, 0, lds, 0, 1, w, lane);
  stage_half(B, gn0, 0, lds, 32768, 0, w, lane);
  stage_half(B, gn0, 0, lds, 32768, 1, w, lane);
  asm volatile("s_waitcnt vmcnt(0)" ::: "memory");
  __builtin_amdgcn_s_barrier();
#pragma unroll
  for (int fi = 0; fi < 4; ++fi)
#pragma unroll
    for (int ks = 0; ks < 2; ++ks)
      a0[fi][ks] = lds_frag(&lds[0], wm * 128 + fi * 16 + ll, ks, lh);
#pragma unroll
  for (int fj = 0; fj < 2; ++fj)
#pragma unroll
    for (int ks = 0; ks < 2; ++ks)
      b0[fj][ks] = lds_frag(&lds[32768], wn * 64 + fj * 16 + ll, ks, lh);
  stage_half(B, gn0, BK, lds, 65536 + 32768, 0, w, lane);
  stage_half(B, gn0, BK, lds, 65536 + 32768, 1, w, lane);
  stage_half(A, gm0, BK, lds, 65536, 0, w, lane);
  // vm outstanding = 6 {B1h0,B1h1,A1h0} -> matches steady state

#pragma unroll 2
  for (int T = 0; T < NT; ++T) {
    const int c = T & 1;
    const int aOff = c * 65536;
    const int bOff = aOff + 32768;
    const int aN = (c ^ 1) * 65536;
    const int bN = aN + 32768;

    // ==== ph1: MFMA QA (a0,b0); prefetch b1; stage A(T+1)h1 ====
    __builtin_amdgcn_s_barrier();
#pragma unroll
    for (int fj = 0; fj < 2; ++fj)
#pragma unroll
      for (int ks = 0; ks < 2; ++ks)
        b1[fj][ks] = lds_frag(&lds[bOff], wn * 64 + 32 + fj * 16 + ll, ks, lh);
    __builtin_amdgcn_s_setprio(1);
#pragma unroll
    for (int fi = 0; fi < 4; ++fi)
#pragma unroll
      for (int fj = 0; fj < 2; ++fj) {
        acc[fi][fj] = MFMA16(a0[fi][0], b0[fj][0], acc[fi][fj]);
        acc[fi][fj] = MFMA16(a0[fi][1], b0[fj][1], acc[fi][fj]);
      }
    __builtin_amdgcn_s_setprio(0);
    if (T < NT - 1)
      stage_half(A, gm0, (T + 1) * BK, lds, aN, 1, w, lane);

    // ==== ph2: MFMA QB (a0,b1); prefetch a1; stage B(T+2)h0 ====
    __builtin_amdgcn_s_barrier();
#pragma unroll
    for (int fi = 0; fi < 4; ++fi)
#pragma unroll
      for (int ks = 0; ks < 2; ++ks)
        a1[fi][ks] = lds_frag(&lds[aOff], wm * 128 + 64 + fi * 16 + ll, ks, lh);
    __builtin_amdgcn_s_setprio(1);
#pragma unroll
    for (int fi = 0; fi < 4; ++fi)
#pragma unroll
      for (int fj = 0; fj < 2; ++fj) {
        acc[fi][2 + fj] = MFMA16(a0[fi][0], b1[fj][0], acc[fi][2 + fj]);
        acc[fi][2 + fj] = MFMA16(a0[fi][1], b1[fj][1], acc[fi][2 + fj]);
      }
    __builtin_amdgcn_s_setprio(0);
    if (T < NT - 2)
      stage_half(B, gn0, (T + 2) * BK, lds, bOff, 0, w, lane);

    // ==== ph3: vmcnt guard for tile T+1; MFMA QC (a1,b0); prefetch a0'; stage B(T+2)h1 ====
    __builtin_amdgcn_s_barrier();
    if (T < NT - 2)
      asm volatile("s_waitcnt vmcnt(2)" ::: "memory");  // drains through A(T+1)h1
    else
      asm volatile("s_waitcnt vmcnt(0)" ::: "memory");
    if (T < NT - 1) {
#pragma unroll
      for (int fi = 0; fi < 4; ++fi)
#pragma unroll
        for (int ks = 0; ks < 2; ++ks)
          a0[fi][ks] = lds_frag(&lds[aN], wm * 128 + fi * 16 + ll, ks, lh);
    }
    __builtin_amdgcn_s_setprio(1);
#pragma unroll
    for (int fi = 0; fi < 4; ++fi)
#pragma unroll
      for (int fj = 0; fj < 2; ++fj) {
        acc[4 + fi][fj] = MFMA16(a1[fi][0], b0[fj][0], acc[4 + fi][fj]);
        acc[4 + fi][fj] = MFMA16(a1[fi][1], b0[fj][1], acc[4 + fi][fj]);
      }
    __builtin_amdgcn_s_setprio(0);
    if (T < NT - 2)
      stage_half(B, gn0, (T + 2) * BK, lds, bOff, 1, w, lane);

    // ==== ph4: MFMA QD (a1,b1); prefetch b0'; stage A(T+2)h0 ====
    __builtin_amdgcn_s_barrier();
    if (T < NT - 1) {
#pragma unroll
      for (int fj = 0; fj < 2; ++fj)
#pragma unroll
        for (int ks = 0; ks < 2; ++ks)
          b0[fj][ks] = lds_frag(&lds[bN], wn * 64 + fj * 16 + ll, ks, lh);
    }
    __builtin_amdgcn_s_setprio(1);
#pragma unroll
    for (int fi = 0; fi < 4; ++fi)
#pragma unroll
      for (int fj = 0; fj < 2; ++fj) {
        acc[4 + fi][2 + fj] = MFMA16(a1[fi][0], b1[fj][0], acc[4 + fi][2 + fj]);
        acc[4 + fi][2 + fj] = MFMA16(a1[fi][1], b1[fj][1], acc[4 + fi][2 + fj]);
      }
    __builtin_amdgcn_s_setprio(0);
    if (T < NT - 2)
      stage_half(A, gm0, (T + 2) * BK, lds, aOff, 0, w, lane);
  }

  // ---- epilogue: y = scale*acc + bias ----
  const float sc = *scale_ptr;
#pragma unroll
  for (int nh = 0; nh < 2; ++nh)
#pragma unroll
    for (int fj = 0; fj < 2; ++fj) {
      const size_t col = gn0 + wn * 64 + nh * 32 + fj * 16 + ll;
      const float bv = bias[col];
#pragma unroll
      for (int mh = 0; mh < 2; ++mh)
#pragma unroll
        for (int fi = 0; fi < 4; ++fi) {
          const size_t row0 = gm0 + wm * 128 + mh * 64 + fi * 16 + lh * 4;
          const f32x4 v = acc[mh * 4 + fi][nh * 2 + fj];
#pragma unroll
          for (int r = 0; r < 4; ++r)
            C[(row0 + r) * N_DIM + col] = sc * v[r] + bv;
        }
    }
}

// ---- fallback (small ws): fused-conversion 128^2 GEMM, known-correct from R0 ----
__global__ __launch_bounds__(256, 2) void gemm_fallback_kernel(
    const float* __restrict__ Aptr, const int* __restrict__ Wptr,
    const float* __restrict__ scale_ptr, const float* __restrict__ zp_ptr,
    const float* __restrict__ bias, float* __restrict__ C) {
  __shared__ unsigned short As[128 * 32];
  __shared__ unsigned short Ws[128 * 32];
  const int t = threadIdx.x;
  const int lane = t & 63;
  const int w = t >> 6;
  const int wm = w >> 1, wn = w & 1;
  const size_t gm0 = (size_t)blockIdx.y * 128;
  const size_t gn0 = (size_t)blockIdx.x * 128;
  f32x4 acc[4][4] = {};
  const float zp = *zp_ptr;
  for (int k0 = 0; k0 < K_DIM; k0 += 32) {
    __syncthreads();
    const int row = t >> 1;
    const int kh = (t & 1) * 16;
    const float* sa = Aptr + (gm0 + row) * (size_t)K_DIM + k0 + kh;
    f32x4 a0 = ((const f32x4*)sa)[0], a1 = ((const f32x4*)sa)[1];
    f32x4 a2 = ((const f32x4*)sa)[2], a3 = ((const f32x4*)sa)[3];
    u16x8 o0, o1;
    o0[0] = f2bf(a0[0]); o0[1] = f2bf(a0[1]); o0[2] = f2bf(a0[2]); o0[3] = f2bf(a0[3]);
    o0[4] = f2bf(a1[0]); o0[5] = f2bf(a1[1]); o0[6] = f2bf(a1[2]); o0[7] = f2bf(a1[3]);
    o1[0] = f2bf(a2[0]); o1[1] = f2bf(a2[1]); o1[2] = f2bf(a2[2]); o1[3] = f2bf(a2[3]);
    o1[4] = f2bf(a3[0]); o1[5] = f2bf(a3[1]); o1[6] = f2bf(a3[2]); o1[7] = f2bf(a3[3]);
    *(u16x8*)&As[row * 32 + kh] = o0;
    *(u16x8*)&As[row * 32 + kh + 8] = o1;
    const int* sw = Wptr + (gn0 + row) * (size_t)K_DIM + k0 + kh;
    i32x4 w0 = ((const i32x4*)sw)[0], w1 = ((const i32x4*)sw)[1];
    i32x4 w2 = ((const i32x4*)sw)[2], w3 = ((const i32x4*)sw)[3];
    u16x8 p0, p1;
    p0[0] = f2bf((float)w0[0] - zp); p0[1] = f2bf((float)w0[1] - zp);
    p0[2] = f2bf((float)w0[2] - zp); p0[3] = f2bf((float)w0[3] - zp);
    p0[4] = f2bf((float)w1[0] - zp); p0[5] = f2bf((float)w1[1] - zp);
    p0[6] = f2bf((float)w1[2] - zp); p0[7] = f2bf((float)w1[3] - zp);
    p1[0] = f2bf((float)w2[0] - zp); p1[1] = f2bf((float)w2[1] - zp);
    p1[2] = f2bf((float)w2[2] - zp); p1[3] = f2bf((float)w2[3] - zp);
    p1[4] = f2bf((float)w3[0] - zp); p1[5] = f2bf((float)w3[1] - zp);
    p1[6] = f2bf((float)w3[2] - zp); p1[7] = f2bf((float)w3[3] - zp);
    *(u16x8*)&Ws[row * 32 + kh] = p0;
    *(u16x8*)&Ws[row * 32 + kh + 8] = p1;
    __syncthreads();
    bf16x8 af[4], bfr[4];
#pragma unroll
    for (int f = 0; f < 4; ++f) {
      af[f] = *(const bf16x8*)&As[(wm * 64 + f * 16 + (lane & 15)) * 32 + (lane >> 4) * 8];
      bfr[f] = *(const bf16x8*)&Ws[(wn * 64 + f * 16 + (lane & 15)) * 32 + (lane >> 4) * 8];
    }
#pragma unroll
    for (int i = 0; i < 4; ++i)
#pragma unroll
      for (int j = 0; j < 4; ++j)
        acc[i][j] = MFMA16(af[i], bfr[j], acc[i][j]);
  }
  const float sc = *scale_ptr;
#pragma unroll
  for (int i = 0; i < 4; ++i) {
    const int rbase = wm * 64 + i * 16 + ((lane >> 4) << 2);
#pragma unroll
    for (int j = 0; j < 4; ++j) {
      const size_t col = gn0 + wn * 64 + j * 16 + (lane & 15);
      const float bv = bias[col];
#pragma unroll
      for (int r = 0; r < 4; ++r)
        C[(gm0 + rbase + r) * N_DIM + col] = sc * acc[i][j][r] + bv;
    }
  }
}

extern "C" void kernel_launch(void* const* d_in, const int* in_sizes, int n_in,
                              void* d_out, int out_size, void* d_ws, size_t ws_size,
                              hipStream_t stream) {
  const float* x = (const float*)d_in[0];
  const int* q = (const int*)d_in[1];
  const float* scale = (const float*)d_in[2];
  const float* zp = (const float*)d_in[3];
  const float* bias = (const float*)d_in[4];
  float* out = (float*)d_out;

  const size_t needA = (size_t)M_DIM * K_DIM * 2;  // 64 MiB
  const size_t needW = (size_t)N_DIM * K_DIM * 2;  // 32 MiB

  if (ws_size >= needA + needW) {
    unsigned short* Abf = (unsigned short*)d_ws;
    unsigned short* Wbf = (unsigned short*)((char*)d_ws + needA);
    cvt_x_kernel<<<(M_DIM * (size_t)K_DIM) / (8 * 256), 256, 0, stream>>>(x, Abf);
    cvt_w_kernel<<<(N_DIM * (size_t)K_DIM) / (8 * 256), 256, 0, stream>>>(q, zp, Wbf);
    dim3 grid(N_DIM / BN, M_DIM / BM);  // 16 x 32 = 512
    gemm8_kernel<<<grid, 512, 0, stream>>>(Abf, Wbf, scale, bias, out);
  } else {
    dim3 grid(N_DIM / 128, M_DIM / 128);
    gemm_fallback_kernel<<<grid, 256, 0, stream>>>(x, q, scale, zp, bias, out);
  }
}

// Round 5
// 282.969 us; speedup vs baseline: 1.8149x; 1.8149x over previous
//
#include <hip/hip_runtime.h>
#include <hip/hip_bf16.h>

// QuantizedLinear: y[m][n] = scale * sum_k x[m][k]*(q[n][k]-zp) + bias[n]
// M=8192, N=4096, K=4096. (q-zp) integer in [-255,255] -> exact in bf16.
// cvt passes -> 256^2 4-phase bf16 MFMA GEMM (R3 sync skeleton) with
// swizzle folded into precomputed per-thread bases + compiler-counted lgkm.

typedef __attribute__((ext_vector_type(8))) __bf16 bf16x8;
typedef __attribute__((ext_vector_type(4))) float f32x4;
typedef __attribute__((ext_vector_type(4))) int i32x4;
typedef __attribute__((ext_vector_type(8))) unsigned short u16x8;

#define M_DIM 8192
#define N_DIM 4096
#define K_DIM 4096
#define BM 256
#define BN 256
#define BK 64
#define NT (K_DIM / BK)

#define MFMA16(A, B, C) __builtin_amdgcn_mfma_f32_16x16x32_bf16(A, B, C, 0, 0, 0)

__device__ __forceinline__ unsigned short f2bf(float f) {
  __hip_bfloat16 h = __float2bfloat16(f);
  unsigned short u;
  __builtin_memcpy(&u, &h, 2);
  return u;
}

// ---- conversion pass 1: x fp32 -> bf16 ----
__global__ __launch_bounds__(256) void cvt_x_kernel(const float* __restrict__ x,
                                                    unsigned short* __restrict__ out) {
  size_t i = (size_t)blockIdx.x * 256 + threadIdx.x;
  f32x4 a = ((const f32x4*)x)[2 * i];
  f32x4 b = ((const f32x4*)x)[2 * i + 1];
  u16x8 o;
  o[0] = f2bf(a[0]); o[1] = f2bf(a[1]); o[2] = f2bf(a[2]); o[3] = f2bf(a[3]);
  o[4] = f2bf(b[0]); o[5] = f2bf(b[1]); o[6] = f2bf(b[2]); o[7] = f2bf(b[3]);
  *(u16x8*)(out + 8 * i) = o;
}

// ---- conversion pass 2: w = (float)q - zp -> bf16 (exact) ----
__global__ __launch_bounds__(256) void cvt_w_kernel(const int* __restrict__ q,
                                                    const float* __restrict__ zp_ptr,
                                                    unsigned short* __restrict__ out) {
  const float zp = *zp_ptr;
  size_t i = (size_t)blockIdx.x * 256 + threadIdx.x;
  i32x4 a = ((const i32x4*)q)[2 * i];
  i32x4 b = ((const i32x4*)q)[2 * i + 1];
  u16x8 o;
  o[0] = f2bf((float)a[0] - zp); o[1] = f2bf((float)a[1] - zp);
  o[2] = f2bf((float)a[2] - zp); o[3] = f2bf((float)a[3] - zp);
  o[4] = f2bf((float)b[0] - zp); o[5] = f2bf((float)b[1] - zp);
  o[6] = f2bf((float)b[2] - zp); o[7] = f2bf((float)b[3] - zp);
  *(u16x8*)(out + 8 * i) = o;
}

// Stage one half-tile (128 rows x 64 bf16 = 16KB): 8 waves x 2 chunks x 1KB.
// Per-thread inverse-swizzled source offsets are folded into s0/s1; the only
// per-call math is a wave-uniform byte offset (Ti*128 + h*1MB).
__device__ __forceinline__ void stage2(const char* s0, const char* s1, char* ldsT,
                                       int h, int Ti, int chunk0, int chunk1) {
  const size_t off = (size_t)Ti * 128 + (size_t)h * 1048576;
  __builtin_amdgcn_global_load_lds(
      (const __attribute__((address_space(1))) void*)(s0 + off),
      (__attribute__((address_space(3))) void*)(ldsT + h * 16384 + chunk0), 16, 0, 0);
  __builtin_amdgcn_global_load_lds(
      (const __attribute__((address_space(1))) void*)(s1 + off),
      (__attribute__((address_space(3))) void*)(ldsT + h * 16384 + chunk1), 16, 0, 0);
}

#define FENCE() asm volatile("" ::: "memory")

// One K-tile = 4 single-barrier phases. pak0/pak1: A fragment bases (ks=0/1)
// for the CURRENT buffer; pbk0/pbk1 same for B. curA/curB/nxtA: staging dests.
__device__ __forceinline__ void ktile(
    int T, const char* pak0, const char* pak1, const char* pbk0, const char* pbk1,
    char* curA, char* curB, char* nxtA,
    const char* srcA0, const char* srcA1, const char* srcB0, const char* srcB1,
    int chunk0, int chunk1, f32x4 (&acc)[8][4]) {
  bf16x8 af[4][2], b0f[2][2], b1f[2][2];

  // ==== ph1: read A-mh0 + B-nh0; stage A(T+1)h1 -> nxtA; MFMA Q(0,0) ====
#pragma unroll
  for (int fi = 0; fi < 4; ++fi) {
    af[fi][0] = *(const bf16x8*)(pak0 + fi * 2048);
    af[fi][1] = *(const bf16x8*)(pak1 + fi * 2048);
  }
#pragma unroll
  for (int fj = 0; fj < 2; ++fj) {
    b0f[fj][0] = *(const bf16x8*)(pbk0 + fj * 2048);
    b0f[fj][1] = *(const bf16x8*)(pbk1 + fj * 2048);
  }
  if (T < NT - 1) stage2(srcA0, srcA1, nxtA, 1, T + 1, chunk0, chunk1);
  if (T < NT - 2) asm volatile("s_waitcnt vmcnt(10)" ::: "memory");
  else            asm volatile("s_waitcnt vmcnt(0)" ::: "memory");
  __builtin_amdgcn_s_barrier();
  FENCE();
  __builtin_amdgcn_s_setprio(1);
#pragma unroll
  for (int fi = 0; fi < 4; ++fi)
#pragma unroll
    for (int fj = 0; fj < 2; ++fj) {
      acc[fi][fj] = MFMA16(af[fi][0], b0f[fj][0], acc[fi][fj]);
      acc[fi][fj] = MFMA16(af[fi][1], b0f[fj][1], acc[fi][fj]);
    }
  __builtin_amdgcn_s_setprio(0);

  // ==== ph2: read B-nh1; MFMA Q(0,1) ====
#pragma unroll
  for (int fj = 0; fj < 2; ++fj) {
    b1f[fj][0] = *(const bf16x8*)(pbk0 + 4096 + fj * 2048);
    b1f[fj][1] = *(const bf16x8*)(pbk1 + 4096 + fj * 2048);
  }
  if (T < NT - 2) asm volatile("s_waitcnt vmcnt(8)" ::: "memory");
  else            asm volatile("s_waitcnt vmcnt(0)" ::: "memory");
  __builtin_amdgcn_s_barrier();
  FENCE();
  __builtin_amdgcn_s_setprio(1);
#pragma unroll
  for (int fi = 0; fi < 4; ++fi)
#pragma unroll
    for (int fj = 0; fj < 2; ++fj) {
      acc[fi][2 + fj] = MFMA16(af[fi][0], b1f[fj][0], acc[fi][2 + fj]);
      acc[fi][2 + fj] = MFMA16(af[fi][1], b1f[fj][1], acc[fi][2 + fj]);
    }
  __builtin_amdgcn_s_setprio(0);

  // ==== ph3: read A-mh1; stage B(T+2)h0 -> curB; MFMA Q(1,1) ====
#pragma unroll
  for (int fi = 0; fi < 4; ++fi) {
    af[fi][0] = *(const bf16x8*)(pak0 + 8192 + fi * 2048);
    af[fi][1] = *(const bf16x8*)(pak1 + 8192 + fi * 2048);
  }
  if (T < NT - 2) stage2(srcB0, srcB1, curB, 0, T + 2, chunk0, chunk1);
  __builtin_amdgcn_s_barrier();
  FENCE();
  __builtin_amdgcn_s_setprio(1);
#pragma unroll
  for (int fi = 0; fi < 4; ++fi)
#pragma unroll
    for (int fj = 0; fj < 2; ++fj) {
      acc[4 + fi][2 + fj] = MFMA16(af[fi][0], b1f[fj][0], acc[4 + fi][2 + fj]);
      acc[4 + fi][2 + fj] = MFMA16(af[fi][1], b1f[fj][1], acc[4 + fi][2 + fj]);
    }
  __builtin_amdgcn_s_setprio(0);

  // ==== ph4: stage B(T+2)h1 + A(T+2)h0 -> cur; MFMA Q(1,0) ====
  if (T < NT - 2) {
    stage2(srcB0, srcB1, curB, 1, T + 2, chunk0, chunk1);
    stage2(srcA0, srcA1, curA, 0, T + 2, chunk0, chunk1);
  }
  if (T < NT - 2) asm volatile("s_waitcnt vmcnt(8)" ::: "memory");
  else            asm volatile("s_waitcnt vmcnt(0)" ::: "memory");
  __builtin_amdgcn_s_barrier();
  FENCE();
  __builtin_amdgcn_s_setprio(1);
#pragma unroll
  for (int fi = 0; fi < 4; ++fi)
#pragma unroll
    for (int fj = 0; fj < 2; ++fj) {
      acc[4 + fi][fj] = MFMA16(af[fi][0], b0f[fj][0], acc[4 + fi][fj]);
      acc[4 + fi][fj] = MFMA16(af[fi][1], b0f[fj][1], acc[4 + fi][fj]);
    }
  __builtin_amdgcn_s_setprio(0);
}

// ---- 256x256 GEMM, 4 phases/K-tile, precomputed swizzled addresses ----
__global__ __launch_bounds__(512, 2) void gemm8_kernel(
    const unsigned short* __restrict__ A, const unsigned short* __restrict__ B,
    const float* __restrict__ scale_ptr, const float* __restrict__ bias,
    float* __restrict__ C) {
  __shared__ __align__(16) char lds[131072];

  const int t = threadIdx.x;
  const int lane = t & 63;
  const int w = t >> 6;      // 0..7
  const int wm = w >> 2;     // 0..1
  const int wn = w & 3;      // 0..3
  const int ll = lane & 15;
  const int lh = lane >> 4;

  // T1: bijective XCD swizzle (nwg = 512, 512 % 8 == 0)
  const int nwg = gridDim.x * gridDim.y;
  const int flat = blockIdx.y * gridDim.x + blockIdx.x;
  const int per = nwg >> 3;
  const int sw = (flat & 7) * per + (flat >> 3);
  const int tn = sw & (N_DIM / BN - 1);
  const int tm = sw / (N_DIM / BN);
  const size_t gm0 = (size_t)tm * BM;
  const size_t gn0 = (size_t)tn * BN;

  // LDS tile bases
  char* lA0 = (char*)lds;
  char* lB0 = (char*)lds + 32768;
  char* lA1 = (char*)lds + 65536;
  char* lB1 = (char*)lds + 98304;

  // Fragment-read bases: swizzle folds to per-thread constant.
  // addr = row*128 + ((lh*16) ^ ((ll&7)<<4) ^ (ks*64)); offsets mh*8192+fi*2048.
  const int sbase = (lh * 16) ^ ((ll & 7) << 4);
  const char* pa0k0 = lA0 + wm * 16384 + ll * 128 + sbase;
  const char* pa0k1 = lA0 + wm * 16384 + ll * 128 + (sbase ^ 64);
  const char* pb0k0 = lB0 + wn * 8192 + ll * 128 + sbase;
  const char* pb0k1 = lB0 + wn * 8192 + ll * 128 + (sbase ^ 64);
  const char* pa1k0 = pa0k0 + 65536;
  const char* pa1k1 = pa0k1 + 65536;
  const char* pb1k0 = pb0k0 + 65536;
  const char* pb1k1 = pb0k1 + 65536;

  // Staging: per-thread inverse-swizzled row/col constants.
  const int rowS0 = w * 16 + (lane >> 3);
  const int rowS1 = w * 16 + 8 + (lane >> 3);
  const int colSB = ((lane & 7) * 16) ^ (((lane >> 3) & 7) << 4);
  const int chunk0 = w * 2048;
  const int chunk1 = w * 2048 + 1024;
  const char* srcA0 = (const char*)A + (gm0 + rowS0) * (size_t)(K_DIM * 2) + colSB;
  const char* srcA1 = (const char*)A + (gm0 + rowS1) * (size_t)(K_DIM * 2) + colSB;
  const char* srcB0 = (const char*)B + (gn0 + rowS0) * (size_t)(K_DIM * 2) + colSB;
  const char* srcB1 = (const char*)B + (gn0 + rowS1) * (size_t)(K_DIM * 2) + colSB;

  f32x4 acc[8][4] = {};  // [mh*4+fi][nh*2+fj]

  // ---- prologue: tile0 (4 halves) + tile1 (B h0,h1 + A h0) = 14 loads ----
  stage2(srcA0, srcA1, lA0, 0, 0, chunk0, chunk1);
  stage2(srcA0, srcA1, lA0, 1, 0, chunk0, chunk1);
  stage2(srcB0, srcB1, lB0, 0, 0, chunk0, chunk1);
  stage2(srcB0, srcB1, lB0, 1, 0, chunk0, chunk1);
  stage2(srcB0, srcB1, lB1, 0, 1, chunk0, chunk1);
  stage2(srcB0, srcB1, lB1, 1, 1, chunk0, chunk1);
  stage2(srcA0, srcA1, lA1, 0, 1, chunk0, chunk1);
  asm volatile("s_waitcnt vmcnt(6)" ::: "memory");  // tile0 complete; 3 halves in flight
  __builtin_amdgcn_s_barrier();
  FENCE();

  for (int T2 = 0; T2 < NT; T2 += 2) {
    ktile(T2, pa0k0, pa0k1, pb0k0, pb0k1, lA0, lB0, lA1,
          srcA0, srcA1, srcB0, srcB1, chunk0, chunk1, acc);
    ktile(T2 + 1, pa1k0, pa1k1, pb1k0, pb1k1, lA1, lB1, lA0,
          srcA0, srcA1, srcB0, srcB1, chunk0, chunk1, acc);
  }

  // ---- epilogue: y = scale*acc + bias ----
  const float sc = *scale_ptr;
#pragma unroll
  for (int nh = 0; nh < 2; ++nh)
#pragma unroll
    for (int fj = 0; fj < 2; ++fj) {
      const size_t col = gn0 + wn * 64 + nh * 32 + fj * 16 + ll;
      const float bv = bias[col];
#pragma unroll
      for (int mh = 0; mh < 2; ++mh)
#pragma unroll
        for (int fi = 0; fi < 4; ++fi) {
          const size_t row0 = gm0 + wm * 128 + mh * 64 + fi * 16 + lh * 4;
          const f32x4 v = acc[mh * 4 + fi][nh * 2 + fj];
#pragma unroll
          for (int r = 0; r < 4; ++r)
            C[(row0 + r) * N_DIM + col] = sc * v[r] + bv;
        }
    }
}

// ---- fallback (small ws): fused-conversion 128^2 GEMM, known-correct from R0 ----
__global__ __launch_bounds__(256, 2) void gemm_fallback_kernel(
    const float* __restrict__ Aptr, const int* __restrict__ Wptr,
    const float* __restrict__ scale_ptr, const float* __restrict__ zp_ptr,
    const float* __restrict__ bias, float* __restrict__ C) {
  __shared__ unsigned short As[128 * 32];
  __shared__ unsigned short Ws[128 * 32];
  const int t = threadIdx.x;
  const int lane = t & 63;
  const int w = t >> 6;
  const int wm = w >> 1, wn = w & 1;
  const size_t gm0 = (size_t)blockIdx.y * 128;
  const size_t gn0 = (size_t)blockIdx.x * 128;
  f32x4 acc[4][4] = {};
  const float zp = *zp_ptr;
  for (int k0 = 0; k0 < K_DIM; k0 += 32) {
    __syncthreads();
    const int row = t >> 1;
    const int kh = (t & 1) * 16;
    const float* sa = Aptr + (gm0 + row) * (size_t)K_DIM + k0 + kh;
    f32x4 a0 = ((const f32x4*)sa)[0], a1 = ((const f32x4*)sa)[1];
    f32x4 a2 = ((const f32x4*)sa)[2], a3 = ((const f32x4*)sa)[3];
    u16x8 o0, o1;
    o0[0] = f2bf(a0[0]); o0[1] = f2bf(a0[1]); o0[2] = f2bf(a0[2]); o0[3] = f2bf(a0[3]);
    o0[4] = f2bf(a1[0]); o0[5] = f2bf(a1[1]); o0[6] = f2bf(a1[2]); o0[7] = f2bf(a1[3]);
    o1[0] = f2bf(a2[0]); o1[1] = f2bf(a2[1]); o1[2] = f2bf(a2[2]); o1[3] = f2bf(a2[3]);
    o1[4] = f2bf(a3[0]); o1[5] = f2bf(a3[1]); o1[6] = f2bf(a3[2]); o1[7] = f2bf(a3[3]);
    *(u16x8*)&As[row * 32 + kh] = o0;
    *(u16x8*)&As[row * 32 + kh + 8] = o1;
    const int* sw = Wptr + (gn0 + row) * (size_t)K_DIM + k0 + kh;
    i32x4 w0 = ((const i32x4*)sw)[0], w1 = ((const i32x4*)sw)[1];
    i32x4 w2 = ((const i32x4*)sw)[2], w3 = ((const i32x4*)sw)[3];
    u16x8 p0, p1;
    p0[0] = f2bf((float)w0[0] - zp); p0[1] = f2bf((float)w0[1] - zp);
    p0[2] = f2bf((float)w0[2] - zp); p0[3] = f2bf((float)w0[3] - zp);
    p0[4] = f2bf((float)w1[0] - zp); p0[5] = f2bf((float)w1[1] - zp);
    p0[6] = f2bf((float)w1[2] - zp); p0[7] = f2bf((float)w1[3] - zp);
    p1[0] = f2bf((float)w2[0] - zp); p1[1] = f2bf((float)w2[1] - zp);
    p1[2] = f2bf((float)w2[2] - zp); p1[3] = f2bf((float)w2[3] - zp);
    p1[4] = f2bf((float)w3[0] - zp); p1[5] = f2bf((float)w3[1] - zp);
    p1[6] = f2bf((float)w3[2] - zp); p1[7] = f2bf((float)w3[3] - zp);
    *(u16x8*)&Ws[row * 32 + kh] = p0;
    *(u16x8*)&Ws[row * 32 + kh + 8] = p1;
    __syncthreads();
    bf16x8 af[4], bfr[4];
#pragma unroll
    for (int f = 0; f < 4; ++f) {
      af[f] = *(const bf16x8*)&As[(wm * 64 + f * 16 + (lane & 15)) * 32 + (lane >> 4) * 8];
      bfr[f] = *(const bf16x8*)&Ws[(wn * 64 + f * 16 + (lane & 15)) * 32 + (lane >> 4) * 8];
    }
#pragma unroll
    for (int i = 0; i < 4; ++i)
#pragma unroll
      for (int j = 0; j < 4; ++j)
        acc[i][j] = MFMA16(af[i], bfr[j], acc[i][j]);
  }
  const float sc = *scale_ptr;
#pragma unroll
  for (int i = 0; i < 4; ++i) {
    const int rbase = wm * 64 + i * 16 + ((lane >> 4) << 2);
#pragma unroll
    for (int j = 0; j < 4; ++j) {
      const size_t col = gn0 + wn * 64 + j * 16 + (lane & 15);
      const float bv = bias[col];
#pragma unroll
      for (int r = 0; r < 4; ++r)
        C[(gm0 + rbase + r) * N_DIM + col] = sc * acc[i][j][r] + bv;
    }
  }
}

extern "C" void kernel_launch(void* const* d_in, const int* in_sizes, int n_in,
                              void* d_out, int out_size, void* d_ws, size_t ws_size,
                              hipStream_t stream) {
  const float* x = (const float*)d_in[0];
  const int* q = (const int*)d_in[1];
  const float* scale = (const float*)d_in[2];
  const float* zp = (const float*)d_in[3];
  const float* bias = (const float*)d_in[4];
  float* out = (float*)d_out;

  const size_t needA = (size_t)M_DIM * K_DIM * 2;  // 64 MiB
  const size_t needW = (size_t)N_DIM * K_DIM * 2;  // 32 MiB

  if (ws_size >= needA + needW) {
    unsigned short* Abf = (unsigned short*)d_ws;
    unsigned short* Wbf = (unsigned short*)((char*)d_ws + needA);
    cvt_x_kernel<<<(M_DIM * (size_t)K_DIM) / (8 * 256), 256, 0, stream>>>(x, Abf);
    cvt_w_kernel<<<(N_DIM * (size_t)K_DIM) / (8 * 256), 256, 0, stream>>>(q, zp, Wbf);
    dim3 grid(N_DIM / BN, M_DIM / BM);  // 16 x 32 = 512
    gemm8_kernel<<<grid, 512, 0, stream>>>(Abf, Wbf, scale, bias, out);
  } else {
    dim3 grid(N_DIM / 128, M_DIM / 128);
    gemm_fallback_kernel<<<grid, 256, 0, stream>>>(x, q, scale, zp, bias, out);
  }
}

// Round 6
// 278.967 us; speedup vs baseline: 1.8410x; 1.0143x over previous
//
#include <hip/hip_runtime.h>
#include <hip/hip_bf16.h>

// QuantizedLinear: y[m][n] = scale * sum_k x[m][k]*(q[n][k]-zp) + bias[n]
// M=8192, N=4096, K=4096. (q-zp) integer in [-255,255] -> exact in bf16.
// cvt passes -> 256^2 bf16 MFMA GEMM, TWO barrier intervals per K-tile
// (32 MFMA per interval), one counted vmcnt(6) per tile, lgkm0 pre-barrier.

typedef __attribute__((ext_vector_type(8))) __bf16 bf16x8;
typedef __attribute__((ext_vector_type(4))) float f32x4;
typedef __attribute__((ext_vector_type(4))) int i32x4;
typedef __attribute__((ext_vector_type(8))) unsigned short u16x8;

#define M_DIM 8192
#define N_DIM 4096
#define K_DIM 4096
#define BM 256
#define BN 256
#define BK 64
#define NT (K_DIM / BK)

#define MFMA16(A, B, C) __builtin_amdgcn_mfma_f32_16x16x32_bf16(A, B, C, 0, 0, 0)

__device__ __forceinline__ unsigned short f2bf(float f) {
  __hip_bfloat16 h = __float2bfloat16(f);
  unsigned short u;
  __builtin_memcpy(&u, &h, 2);
  return u;
}

// ---- conversion pass 1: x fp32 -> bf16 ----
__global__ __launch_bounds__(256) void cvt_x_kernel(const float* __restrict__ x,
                                                    unsigned short* __restrict__ out) {
  size_t i = (size_t)blockIdx.x * 256 + threadIdx.x;
  f32x4 a = ((const f32x4*)x)[2 * i];
  f32x4 b = ((const f32x4*)x)[2 * i + 1];
  u16x8 o;
  o[0] = f2bf(a[0]); o[1] = f2bf(a[1]); o[2] = f2bf(a[2]); o[3] = f2bf(a[3]);
  o[4] = f2bf(b[0]); o[5] = f2bf(b[1]); o[6] = f2bf(b[2]); o[7] = f2bf(b[3]);
  *(u16x8*)(out + 8 * i) = o;
}

// ---- conversion pass 2: w = (float)q - zp -> bf16 (exact) ----
__global__ __launch_bounds__(256) void cvt_w_kernel(const int* __restrict__ q,
                                                    const float* __restrict__ zp_ptr,
                                                    unsigned short* __restrict__ out) {
  const float zp = *zp_ptr;
  size_t i = (size_t)blockIdx.x * 256 + threadIdx.x;
  i32x4 a = ((const i32x4*)q)[2 * i];
  i32x4 b = ((const i32x4*)q)[2 * i + 1];
  u16x8 o;
  o[0] = f2bf((float)a[0] - zp); o[1] = f2bf((float)a[1] - zp);
  o[2] = f2bf((float)a[2] - zp); o[3] = f2bf((float)a[3] - zp);
  o[4] = f2bf((float)b[0] - zp); o[5] = f2bf((float)b[1] - zp);
  o[6] = f2bf((float)b[2] - zp); o[7] = f2bf((float)b[3] - zp);
  *(u16x8*)(out + 8 * i) = o;
}

// Stage one half-tile (128 rows x 64 bf16 = 16KB): 8 waves x 2 chunks x 1KB.
// Per-thread inverse-swizzled source offsets folded into s0/s1.
__device__ __forceinline__ void stage2(const char* s0, const char* s1, char* ldsT,
                                       int h, int Ti, int chunk0, int chunk1) {
  const size_t off = (size_t)Ti * 128 + (size_t)h * 1048576;
  __builtin_amdgcn_global_load_lds(
      (const __attribute__((address_space(1))) void*)(s0 + off),
      (__attribute__((address_space(3))) void*)(ldsT + h * 16384 + chunk0), 16, 0, 0);
  __builtin_amdgcn_global_load_lds(
      (const __attribute__((address_space(1))) void*)(s1 + off),
      (__attribute__((address_space(3))) void*)(ldsT + h * 16384 + chunk1), 16, 0, 0);
}

// One K-tile = 2 barrier intervals of 32 MFMA each.
// Sync invariant: every wave drains its ds_reads (lgkmcnt(0)) BEFORE each
// barrier -> any stage issued after the barrier cannot clobber a pending read.
__device__ __forceinline__ void ktile(
    int T, const char* pak0, const char* pak1, const char* pbk0, const char* pbk1,
    char* curA, char* curB, char* nxtA,
    const char* srcA0, const char* srcA1, const char* srcB0, const char* srcB1,
    int chunk0, int chunk1, f32x4 (&acc)[8][4]) {
  bf16x8 af[4][2], b0f[2][2], b1f[2][2];

  // ==== interval 1: reads a_lo + b0 + b1; stage A(T+1)h1; MFMA Q(0,0)+Q(0,1) ====
#pragma unroll
  for (int fi = 0; fi < 4; ++fi) {
    af[fi][0] = *(const bf16x8*)(pak0 + fi * 2048);
    af[fi][1] = *(const bf16x8*)(pak1 + fi * 2048);
  }
#pragma unroll
  for (int fj = 0; fj < 2; ++fj) {
    b0f[fj][0] = *(const bf16x8*)(pbk0 + fj * 2048);
    b0f[fj][1] = *(const bf16x8*)(pbk1 + fj * 2048);
    b1f[fj][0] = *(const bf16x8*)(pbk0 + 4096 + fj * 2048);
    b1f[fj][1] = *(const bf16x8*)(pbk1 + 4096 + fj * 2048);
  }
  if (T < NT - 1) stage2(srcA0, srcA1, nxtA, 1, T + 1, chunk0, chunk1);
  asm volatile("s_waitcnt lgkmcnt(0)" ::: "memory");
  __builtin_amdgcn_s_barrier();
  __builtin_amdgcn_s_setprio(1);
#pragma unroll
  for (int fi = 0; fi < 4; ++fi)
#pragma unroll
    for (int fj = 0; fj < 2; ++fj) {
      acc[fi][fj] = MFMA16(af[fi][0], b0f[fj][0], acc[fi][fj]);
      acc[fi][fj] = MFMA16(af[fi][1], b0f[fj][1], acc[fi][fj]);
    }
#pragma unroll
  for (int fi = 0; fi < 4; ++fi)
#pragma unroll
    for (int fj = 0; fj < 2; ++fj) {
      acc[fi][2 + fj] = MFMA16(af[fi][0], b1f[fj][0], acc[fi][2 + fj]);
      acc[fi][2 + fj] = MFMA16(af[fi][1], b1f[fj][1], acc[fi][2 + fj]);
    }
  __builtin_amdgcn_s_setprio(0);

  // ==== interval 2: reads a_hi; stage B(T+2)h0,h1 + A(T+2)h0; vmcnt(6); MFMA Q(1,1)+Q(1,0) ====
#pragma unroll
  for (int fi = 0; fi < 4; ++fi) {
    af[fi][0] = *(const bf16x8*)(pak0 + 8192 + fi * 2048);
    af[fi][1] = *(const bf16x8*)(pak1 + 8192 + fi * 2048);
  }
  if (T < NT - 2) {
    stage2(srcB0, srcB1, curB, 0, T + 2, chunk0, chunk1);
    stage2(srcB0, srcB1, curB, 1, T + 2, chunk0, chunk1);
    stage2(srcA0, srcA1, curA, 0, T + 2, chunk0, chunk1);
  }
  if (T < NT - 2) asm volatile("s_waitcnt vmcnt(6)" ::: "memory");
  else            asm volatile("s_waitcnt vmcnt(0)" ::: "memory");
  asm volatile("s_waitcnt lgkmcnt(0)" ::: "memory");
  __builtin_amdgcn_s_barrier();
  __builtin_amdgcn_s_setprio(1);
#pragma unroll
  for (int fi = 0; fi < 4; ++fi)
#pragma unroll
    for (int fj = 0; fj < 2; ++fj) {
      acc[4 + fi][2 + fj] = MFMA16(af[fi][0], b1f[fj][0], acc[4 + fi][2 + fj]);
      acc[4 + fi][2 + fj] = MFMA16(af[fi][1], b1f[fj][1], acc[4 + fi][2 + fj]);
    }
#pragma unroll
  for (int fi = 0; fi < 4; ++fi)
#pragma unroll
    for (int fj = 0; fj < 2; ++fj) {
      acc[4 + fi][fj] = MFMA16(af[fi][0], b0f[fj][0], acc[4 + fi][fj]);
      acc[4 + fi][fj] = MFMA16(af[fi][1], b0f[fj][1], acc[4 + fi][fj]);
    }
  __builtin_amdgcn_s_setprio(0);
}

// ---- 256x256 GEMM, 2 barrier intervals per K-tile, precomputed swizzled addrs ----
__global__ __launch_bounds__(512, 2) void gemm8_kernel(
    const unsigned short* __restrict__ A, const unsigned short* __restrict__ B,
    const float* __restrict__ scale_ptr, const float* __restrict__ bias,
    float* __restrict__ C) {
  __shared__ __align__(16) char lds[131072];

  const int t = threadIdx.x;
  const int lane = t & 63;
  const int w = t >> 6;      // 0..7
  const int wm = w >> 2;     // 0..1
  const int wn = w & 3;      // 0..3
  const int ll = lane & 15;
  const int lh = lane >> 4;

  // T1: bijective XCD swizzle (nwg = 512, 512 % 8 == 0)
  const int nwg = gridDim.x * gridDim.y;
  const int flat = blockIdx.y * gridDim.x + blockIdx.x;
  const int per = nwg >> 3;
  const int sw = (flat & 7) * per + (flat >> 3);
  const int tn = sw & (N_DIM / BN - 1);
  const int tm = sw / (N_DIM / BN);
  const size_t gm0 = (size_t)tm * BM;
  const size_t gn0 = (size_t)tn * BN;

  // LDS tile bases
  char* lA0 = (char*)lds;
  char* lB0 = (char*)lds + 32768;
  char* lA1 = (char*)lds + 65536;
  char* lB1 = (char*)lds + 98304;

  // Fragment-read bases: swizzle folds to per-thread constant.
  const int sbase = (lh * 16) ^ ((ll & 7) << 4);
  const char* pa0k0 = lA0 + wm * 16384 + ll * 128 + sbase;
  const char* pa0k1 = lA0 + wm * 16384 + ll * 128 + (sbase ^ 64);
  const char* pb0k0 = lB0 + wn * 8192 + ll * 128 + sbase;
  const char* pb0k1 = lB0 + wn * 8192 + ll * 128 + (sbase ^ 64);
  const char* pa1k0 = pa0k0 + 65536;
  const char* pa1k1 = pa0k1 + 65536;
  const char* pb1k0 = pb0k0 + 65536;
  const char* pb1k1 = pb0k1 + 65536;

  // Staging: per-thread inverse-swizzled row/col constants.
  const int rowS0 = w * 16 + (lane >> 3);
  const int rowS1 = w * 16 + 8 + (lane >> 3);
  const int colSB = ((lane & 7) * 16) ^ (((lane >> 3) & 7) << 4);
  const int chunk0 = w * 2048;
  const int chunk1 = w * 2048 + 1024;
  const char* srcA0 = (const char*)A + (gm0 + rowS0) * (size_t)(K_DIM * 2) + colSB;
  const char* srcA1 = (const char*)A + (gm0 + rowS1) * (size_t)(K_DIM * 2) + colSB;
  const char* srcB0 = (const char*)B + (gn0 + rowS0) * (size_t)(K_DIM * 2) + colSB;
  const char* srcB1 = (const char*)B + (gn0 + rowS1) * (size_t)(K_DIM * 2) + colSB;

  f32x4 acc[8][4] = {};  // [mh*4+fi][nh*2+fj]

  // ---- prologue: tile0 (4 halves) + tile1 (B h0,h1 + A h0) = 14 loads ----
  stage2(srcA0, srcA1, lA0, 0, 0, chunk0, chunk1);
  stage2(srcA0, srcA1, lA0, 1, 0, chunk0, chunk1);
  stage2(srcB0, srcB1, lB0, 0, 0, chunk0, chunk1);
  stage2(srcB0, srcB1, lB0, 1, 0, chunk0, chunk1);
  stage2(srcB0, srcB1, lB1, 0, 1, chunk0, chunk1);
  stage2(srcB0, srcB1, lB1, 1, 1, chunk0, chunk1);
  stage2(srcA0, srcA1, lA1, 0, 1, chunk0, chunk1);
  asm volatile("s_waitcnt vmcnt(6)" ::: "memory");  // tile0 complete; 3 halves in flight
  __builtin_amdgcn_s_barrier();

  for (int T2 = 0; T2 < NT; T2 += 2) {
    ktile(T2, pa0k0, pa0k1, pb0k0, pb0k1, lA0, lB0, lA1,
          srcA0, srcA1, srcB0, srcB1, chunk0, chunk1, acc);
    ktile(T2 + 1, pa1k0, pa1k1, pb1k0, pb1k1, lA1, lB1, lA0,
          srcA0, srcA1, srcB0, srcB1, chunk0, chunk1, acc);
  }

  // ---- epilogue: y = scale*acc + bias ----
  const float sc = *scale_ptr;
#pragma unroll
  for (int nh = 0; nh < 2; ++nh)
#pragma unroll
    for (int fj = 0; fj < 2; ++fj) {
      const size_t col = gn0 + wn * 64 + nh * 32 + fj * 16 + ll;
      const float bv = bias[col];
#pragma unroll
      for (int mh = 0; mh < 2; ++mh)
#pragma unroll
        for (int fi = 0; fi < 4; ++fi) {
          const size_t row0 = gm0 + wm * 128 + mh * 64 + fi * 16 + lh * 4;
          const f32x4 v = acc[mh * 4 + fi][nh * 2 + fj];
#pragma unroll
          for (int r = 0; r < 4; ++r)
            C[(row0 + r) * N_DIM + col] = sc * v[r] + bv;
        }
    }
}

// ---- fallback (small ws): fused-conversion 128^2 GEMM, known-correct from R0 ----
__global__ __launch_bounds__(256, 2) void gemm_fallback_kernel(
    const float* __restrict__ Aptr, const int* __restrict__ Wptr,
    const float* __restrict__ scale_ptr, const float* __restrict__ zp_ptr,
    const float* __restrict__ bias, float* __restrict__ C) {
  __shared__ unsigned short As[128 * 32];
  __shared__ unsigned short Ws[128 * 32];
  const int t = threadIdx.x;
  const int lane = t & 63;
  const int w = t >> 6;
  const int wm = w >> 1, wn = w & 1;
  const size_t gm0 = (size_t)blockIdx.y * 128;
  const size_t gn0 = (size_t)blockIdx.x * 128;
  f32x4 acc[4][4] = {};
  const float zp = *zp_ptr;
  for (int k0 = 0; k0 < K_DIM; k0 += 32) {
    __syncthreads();
    const int row = t >> 1;
    const int kh = (t & 1) * 16;
    const float* sa = Aptr + (gm0 + row) * (size_t)K_DIM + k0 + kh;
    f32x4 a0 = ((const f32x4*)sa)[0], a1 = ((const f32x4*)sa)[1];
    f32x4 a2 = ((const f32x4*)sa)[2], a3 = ((const f32x4*)sa)[3];
    u16x8 o0, o1;
    o0[0] = f2bf(a0[0]); o0[1] = f2bf(a0[1]); o0[2] = f2bf(a0[2]); o0[3] = f2bf(a0[3]);
    o0[4] = f2bf(a1[0]); o0[5] = f2bf(a1[1]); o0[6] = f2bf(a1[2]); o0[7] = f2bf(a1[3]);
    o1[0] = f2bf(a2[0]); o1[1] = f2bf(a2[1]); o1[2] = f2bf(a2[2]); o1[3] = f2bf(a2[3]);
    o1[4] = f2bf(a3[0]); o1[5] = f2bf(a3[1]); o1[6] = f2bf(a3[2]); o1[7] = f2bf(a3[3]);
    *(u16x8*)&As[row * 32 + kh] = o0;
    *(u16x8*)&As[row * 32 + kh + 8] = o1;
    const int* sw = Wptr + (gn0 + row) * (size_t)K_DIM + k0 + kh;
    i32x4 w0 = ((const i32x4*)sw)[0], w1 = ((const i32x4*)sw)[1];
    i32x4 w2 = ((const i32x4*)sw)[2], w3 = ((const i32x4*)sw)[3];
    u16x8 p0, p1;
    p0[0] = f2bf((float)w0[0] - zp); p0[1] = f2bf((float)w0[1] - zp);
    p0[2] = f2bf((float)w0[2] - zp); p0[3] = f2bf((float)w0[3] - zp);
    p0[4] = f2bf((float)w1[0] - zp); p0[5] = f2bf((float)w1[1] - zp);
    p0[6] = f2bf((float)w1[2] - zp); p0[7] = f2bf((float)w1[3] - zp);
    p1[0] = f2bf((float)w2[0] - zp); p1[1] = f2bf((float)w2[1] - zp);
    p1[2] = f2bf((float)w2[2] - zp); p1[3] = f2bf((float)w2[3] - zp);
    p1[4] = f2bf((float)w3[0] - zp); p1[5] = f2bf((float)w3[1] - zp);
    p1[6] = f2bf((float)w3[2] - zp); p1[7] = f2bf((float)w3[3] - zp);
    *(u16x8*)&Ws[row * 32 + kh] = p0;
    *(u16x8*)&Ws[row * 32 + kh + 8] = p1;
    __syncthreads();
    bf16x8 af[4], bfr[4];
#pragma unroll
    for (int f = 0; f < 4; ++f) {
      af[f] = *(const bf16x8*)&As[(wm * 64 + f * 16 + (lane & 15)) * 32 + (lane >> 4) * 8];
      bfr[f] = *(const bf16x8*)&Ws[(wn * 64 + f * 16 + (lane & 15)) * 32 + (lane >> 4) * 8];
    }
#pragma unroll
    for (int i = 0; i < 4; ++i)
#pragma unroll
      for (int j = 0; j < 4; ++j)
        acc[i][j] = MFMA16(af[i], bfr[j], acc[i][j]);
  }
  const float sc = *scale_ptr;
#pragma unroll
  for (int i = 0; i < 4; ++i) {
    const int rbase = wm * 64 + i * 16 + ((lane >> 4) << 2);
#pragma unroll
    for (int j = 0; j < 4; ++j) {
      const size_t col = gn0 + wn * 64 + j * 16 + (lane & 15);
      const float bv = bias[col];
#pragma unroll
      for (int r = 0; r < 4; ++r)
        C[(gm0 + rbase + r) * N_DIM + col] = sc * acc[i][j][r] + bv;
    }
  }
}

extern "C" void kernel_launch(void* const* d_in, const int* in_sizes, int n_in,
                              void* d_out, int out_size, void* d_ws, size_t ws_size,
                              hipStream_t stream) {
  const float* x = (const float*)d_in[0];
  const int* q = (const int*)d_in[1];
  const float* scale = (const float*)d_in[2];
  const float* zp = (const float*)d_in[3];
  const float* bias = (const float*)d_in[4];
  float* out = (float*)d_out;

  const size_t needA = (size_t)M_DIM * K_DIM * 2;  // 64 MiB
  const size_t needW = (size_t)N_DIM * K_DIM * 2;  // 32 MiB

  if (ws_size >= needA + needW) {
    unsigned short* Abf = (unsigned short*)d_ws;
    unsigned short* Wbf = (unsigned short*)((char*)d_ws + needA);
    cvt_x_kernel<<<(M_DIM * (size_t)K_DIM) / (8 * 256), 256, 0, stream>>>(x, Abf);
    cvt_w_kernel<<<(N_DIM * (size_t)K_DIM) / (8 * 256), 256, 0, stream>>>(q, zp, Wbf);
    dim3 grid(N_DIM / BN, M_DIM / BM);  // 16 x 32 = 512
    gemm8_kernel<<<grid, 512, 0, stream>>>(Abf, Wbf, scale, bias, out);
  } else {
    dim3 grid(N_DIM / 128, M_DIM / 128);
    gemm_fallback_kernel<<<grid, 256, 0, stream>>>(x, q, scale, zp, bias, out);
  }
}